// Round 2
// 9203.735 us; speedup vs baseline: 1.0274x; 1.0274x over previous
//
#include <hip/hip_runtime.h>
#include <math.h>

#define B_    32
#define TE    1024
#define TD    512
#define E_    512
#define F_    32
#define K_    31
#define KH    15
#define CHUNK 64
#define NCH   (TE / CHUNK)        // 16 chunks per batch row
#define NBLK  (B_ * NCH)          // 512 blocks = 2/CU x 256 CU, all resident

typedef __attribute__((ext_vector_type(8))) short short8;
typedef __attribute__((ext_vector_type(4))) float f32x4;

__device__ __forceinline__ unsigned short f2bf(float x) {   // RNE f32->bf16
    unsigned u = __float_as_uint(x);
    unsigned r = (u + 0x7fffu + ((u >> 16) & 1u)) >> 16;
    return (unsigned short)r;
}
__device__ __forceinline__ float bf2f(unsigned short h) {
    return __uint_as_float(((unsigned)h) << 16);
}

// Agent-scope cache-bypassing accessors: cross-XCD coherent without any
// cache-wide invalidate, so enc stays L1/L2-cacheable across steps.
__device__ __forceinline__ float gldf(const float* p) {
    return __hip_atomic_load(p, __ATOMIC_RELAXED, __HIP_MEMORY_SCOPE_AGENT);
}
__device__ __forceinline__ void gstf(float* p, float v) {
    __hip_atomic_store(p, v, __ATOMIC_RELAXED, __HIP_MEMORY_SCOPE_AGENT);
}

// ---------------------------------------------------------------------------
// Prologue (once per call): w_loc (F,U row-major) -> transposed bf16 hi/lo
// [u][c] for direct B-fragment loads.  Also zero-inits the step flags
// (agent-scope stores so all XCDs observe them).
// ---------------------------------------------------------------------------
__global__ void prep_kernel(const float* __restrict__ wloc,
                            unsigned short* __restrict__ WTh,
                            unsigned short* __restrict__ WTl,
                            int* __restrict__ flags)
{
    const int u = threadIdx.x;                 // 512 threads
    #pragma unroll
    for (int c = 0; c < F_; ++c) {
        float x = wloc[c * 512 + u];
        unsigned short h = f2bf(x);
        float lo = x - bf2f(h);
        WTh[u * F_ + c] = h;
        WTl[u * F_ + c] = f2bf(lo);
    }
    __hip_atomic_store(&flags[u], 0, __ATOMIC_RELAXED, __HIP_MEMORY_SCOPE_AGENT);
}

// ---------------------------------------------------------------------------
// Persistent kernel (PLAIN launch; co-residency by resource arithmetic:
// launch_bounds(512,4) -> <=128 VGPR -> 2 blocks/CU; LDS 15.4KB*2 << 160KB;
// grid = 2*256 exactly). One launch runs all TD steps.
// Inter-step sync = per-batch flag barrier (16 blocks) via agent-scope
// atomics. Parity double-buffer for pr/pa/Ps: clobber of parity p data by a
// neighbor's next same-parity write (iteration s+1) happens only after it
// passes wait(flags>=s+1), i.e. after our flag-publish at end of iteration s,
// which is after our reads in phase 1 of iteration s -> zero effective skew.
// Own chunk's pr/pa live in LDS across steps; only halo+Ps cross blocks.
// ---------------------------------------------------------------------------
__global__ __launch_bounds__(512, 4)
void persist_kernel(const float* __restrict__ enc,   // B,TE,E
                    const float* __restrict__ dec,   // B,TD,E
                    const float* __restrict__ cw,    // K,1,F
                    const float* __restrict__ cb,    // F
                    const unsigned short* __restrict__ WTh, // U,F bf16 hi
                    const unsigned short* __restrict__ WTl, // U,F bf16 lo
                    const float* __restrict__ va,    // U
                    const float* __restrict__ ba,    // U
                    float* __restrict__ prG,         // 2,B,TE   exp(e)
                    float* __restrict__ paG,         // 2,B,TE   cum align
                    float* __restrict__ PsG,         // 2,B,NCH  partial sums
                    float* __restrict__ eout,        // B,TD,TE
                    int*   __restrict__ flags)       // B,NCH  steps completed
{
    __shared__ __align__(16) unsigned short fThS[CHUNK * F_]; // A-frag hi [t][c]
    __shared__ __align__(16) unsigned short fTlS[CHUNK * F_]; // A-frag lo
    __shared__ float cwS[K_ * F_];
    __shared__ float paW[CHUNK + 2 * KH + 4];                 // 98
    __shared__ float redT[CHUNK][9];                          // [t][wave], pad
    __shared__ float prS[CHUNK];                              // own exp(e), s-1
    __shared__ float paS[CHUNK];                              // own cum align

    const int tid   = threadIdx.x;
    const int g     = tid & 63;
    const int w     = tid >> 6;               // wave 0..7
    const int q     = g >> 4;                 // quad 0..3
    const int n16   = g & 15;
    const int b     = blockIdx.x >> 4;
    const int chunk = blockIdx.x & 15;
    const int t0    = chunk * CHUNK;
    const float L2E = 1.4426950408889634f;
    const float KK  = 2.885390081777927f;     // 2*log2(e)

    // ---- hoisted: B-fragments, va/ba, conv weights (once per session) ----
    short8 bh[4], bl[4];
    int uu[4]; float vv[4], baR[4];
    #pragma unroll
    for (int ut = 0; ut < 4; ++ut) {
        uu[ut]  = w * 64 + ut * 16 + n16;
        bh[ut]  = ((const short8*)WTh)[uu[ut] * 4 + q];
        bl[ut]  = ((const short8*)WTl)[uu[ut] * 4 + q];
        vv[ut]  = va[uu[ut]];
        baR[ut] = ba[uu[ut]];
    }
    for (int i = tid; i < K_ * F_; i += 512) cwS[i] = cw[i];
    const float cbR = cb[tid & 31];

    int* myf = flags + b * NCH;
    const size_t rowB = (size_t)b * TE + t0;

    for (int s = 0; s < TD; ++s) {
        const int rp = (s + 1) & 1;           // parity of step s-1 buffers
        const int wp = s & 1;                 // parity of step s buffers

        // prefetch query row (no dependency on sync -> hides latency)
        const float* qrow = dec + ((size_t)b * TD + s) * E_;
        float qb[4];
        #pragma unroll
        for (int ut = 0; ut < 4; ++ut) qb[ut] = qrow[uu[ut]] + baR[ut];

        if (s == 0) {
            if (tid < CHUNK + 2 * KH + 4) paW[tid] = 0.0f;
            if (tid < CHUNK) {
                paS[tid] = 0.0f;
                gstf(&paG[wp * (B_ * TE) + rowB + tid], 0.0f);
            }
        } else {
            // ---- per-batch barrier: all 16 chunks finished step s-1 ----
            if (tid < NCH) {
                while (__hip_atomic_load(&myf[tid], __ATOMIC_RELAXED,
                                         __HIP_MEMORY_SCOPE_AGENT) < s)
                    __builtin_amdgcn_s_sleep(8);
            }
            __syncthreads();

            // per-wave redundant Ps sum (no extra barrier)
            float S = 0.0f;
            if (g < 16) S = gldf(&PsG[rp * (B_ * NCH) + b * NCH + g]);
            S += __shfl_xor(S, 1); S += __shfl_xor(S, 2);
            S += __shfl_xor(S, 4); S += __shfl_xor(S, 8);
            S = __shfl(S, 0);
            const float inv = 1.0f / S;

            if (tid < CHUNK) {
                // own chunk: finish softmax s-1, update cum align, publish
                float pn  = prS[tid] * inv;
                float pan = paS[tid] + pn;
                paS[tid]      = pan;
                paW[KH + tid] = pan;
                eout[((size_t)b * TD + (s - 1)) * TE + t0 + tid] = pn;
                gstf(&paG[wp * (B_ * TE) + rowB + tid], pan);
            } else if (tid < CHUNK + 2 * KH) {
                // halo from neighbors (published step s-1 data)
                int hh = tid - CHUNK;                       // 0..29
                int t  = (hh < KH) ? (t0 - KH + hh) : (t0 + CHUNK + (hh - KH));
                int wi = (hh < KH) ? hh : (CHUNK + hh);
                float v = 0.0f;
                if (t >= 0 && t < TE) {
                    size_t off = (size_t)rp * (B_ * TE) + (size_t)b * TE + t;
                    v = gldf(&paG[off]) + gldf(&prG[off]) * inv;
                }
                paW[wi] = v;
            } else if (tid < CHUNK + 2 * KH + 4) {
                paW[tid] = 0.0f;                            // pad 94..97
            }
        }
        __syncthreads();

        // ---- conv -> fT bf16 hi/lo in A-operand layout [t][c] ----
        {
            const int c    = tid & 31;
            const int ts   = tid >> 5;            // 0..15, 4 t each
            const int base = ts * 4;
            float pw[34];
            #pragma unroll
            for (int m = 0; m < 34; ++m) pw[m] = paW[base + m];
            float a0 = cbR, a1 = cbR, a2 = cbR, a3 = cbR;
            #pragma unroll
            for (int k = 0; k < K_; ++k) {
                float wv = cwS[k * F_ + c];
                a0 = fmaf(wv, pw[k],     a0);
                a1 = fmaf(wv, pw[k + 1], a1);
                a2 = fmaf(wv, pw[k + 2], a2);
                a3 = fmaf(wv, pw[k + 3], a3);
            }
            float av[4] = {a0, a1, a2, a3};
            #pragma unroll
            for (int i = 0; i < 4; ++i) {
                unsigned short h = f2bf(av[i]);
                fThS[(base + i) * F_ + c] = h;
                fTlS[(base + i) * F_ + c] = f2bf(av[i] - bf2f(h));
            }
        }
        __syncthreads();

        // ---- MFMA matmul + fused epilogue, one t-tile at a time ----
        const short8* AH = (const short8*)fThS;
        const short8* AL = (const short8*)fTlS;
        #pragma unroll
        for (int tt = 0; tt < 4; ++tt) {
            short8 ah = AH[(tt * 16 + n16) * 4 + q];
            short8 al = AL[(tt * 16 + n16) * 4 + q];
            f32x4 acc[4];
            #pragma unroll
            for (int ut = 0; ut < 4; ++ut) {
                acc[ut] = (f32x4){0, 0, 0, 0};
                acc[ut] = __builtin_amdgcn_mfma_f32_16x16x32_bf16(ah, bh[ut], acc[ut], 0, 0, 0);
                acc[ut] = __builtin_amdgcn_mfma_f32_16x16x32_bf16(al, bh[ut], acc[ut], 0, 0, 0);
                acc[ut] = __builtin_amdgcn_mfma_f32_16x16x32_bf16(ah, bl[ut], acc[ut], 0, 0, 0);
            }
            #pragma unroll
            for (int r = 0; r < 4; ++r) {
                const int tl = tt * 16 + q * 4 + r;
                const float* erow = enc + ((size_t)b * TE + t0 + tl) * E_;
                float sa = 0.0f;
                #pragma unroll
                for (int ut = 0; ut < 4; ++ut) {
                    float x  = acc[ut][r] + erow[uu[ut]] + qb[ut];
                    float rr = __builtin_amdgcn_exp2f(x * KK);       // e^{2x}
                    float th = fmaf(-2.0f, __builtin_amdgcn_rcpf(rr + 1.0f), 1.0f);
                    sa = fmaf(vv[ut], th, sa);
                }
                sa += __shfl_xor(sa, 1);
                sa += __shfl_xor(sa, 2);
                sa += __shfl_xor(sa, 4);
                sa += __shfl_xor(sa, 8);
                if (n16 == 0) redT[tl][w] = sa;
            }
        }
        __syncthreads();

        // ---- final: sum 8 wave-partials per t, exp, publish pr + Ps ----
        // (all publishes are wave 0's -> its vmcnt(0) drains them all)
        if (tid < CHUNK) {
            float e = 0.0f;
            #pragma unroll
            for (int k = 0; k < 8; ++k) e += redT[tid][k];
            // max-free softmax: |e| <= sum|v_a| <= 25.6 -> exp2 arg <= 37
            float p = __builtin_amdgcn_exp2f(e * L2E);
            prS[tid] = p;
            gstf(&prG[wp * (B_ * TE) + rowB + tid], p);
            float sp = p;
            #pragma unroll
            for (int off = 32; off; off >>= 1) sp += __shfl_xor(sp, off);
            if (tid == 0) {
                gstf(&PsG[wp * (B_ * NCH) + b * NCH + chunk], sp);
                asm volatile("s_waitcnt vmcnt(0)" ::: "memory");
                __hip_atomic_store(&myf[chunk], s + 1, __ATOMIC_RELAXED,
                                   __HIP_MEMORY_SCOPE_AGENT);
            }
        }
        // no trailing barrier needed: next iter's post-wait __syncthreads
        // orders waves 1..7 behind wave 0; LDS hazards covered by the
        // per-phase barriers (prS/paS/redT/paW/fT readers analyzed above).
    }

    // ---- tail: normalize last step (parity (TD-1)&1 == 1) into eout ----
    if (tid < NCH) {
        while (__hip_atomic_load(&myf[tid], __ATOMIC_RELAXED,
                                 __HIP_MEMORY_SCOPE_AGENT) < TD)
            __builtin_amdgcn_s_sleep(8);
    }
    __syncthreads();
    if (tid < CHUNK) {
        float S = 0.0f;
        if (g < 16) S = gldf(&PsG[1 * (B_ * NCH) + b * NCH + g]);
        S += __shfl_xor(S, 1); S += __shfl_xor(S, 2);
        S += __shfl_xor(S, 4); S += __shfl_xor(S, 8);
        S = __shfl(S, 0);
        float pn = prS[tid] * (1.0f / S);
        eout[((size_t)b * TD + (TD - 1)) * TE + t0 + tid] = pn;
    }
}

// ---------------------------------------------------------------------------
// Context matmul: c[b,d,e] = sum_t eo[b,d,t] * enc[b,t,e]
// ---------------------------------------------------------------------------
__global__ __launch_bounds__(256)
void context_kernel(const float* __restrict__ eo,   // B,TD,TE
                    const float* __restrict__ enc,  // B,TE,E
                    float* __restrict__ cout)       // B,TD,E
{
    __shared__ float eoT[64][36];
    const int b = blockIdx.y, d0 = blockIdx.x * 32, tid = threadIdx.x;

    float2 acc[32];
    #pragma unroll
    for (int d = 0; d < 32; ++d) { acc[d].x = 0.0f; acc[d].y = 0.0f; }

    for (int tc = 0; tc < TE / 64; ++tc) {
        __syncthreads();
        #pragma unroll
        for (int r = 0; r < 8; ++r) {
            int lin = r * 256 + tid;
            int d = lin >> 6, t = lin & 63;
            eoT[t][d] = eo[((size_t)b * TD + d0 + d) * TE + tc * 64 + t];
        }
        __syncthreads();
        #pragma unroll 4
        for (int t = 0; t < 64; ++t) {
            float2 ev = *(const float2*)&enc[((size_t)b * TE + tc * 64 + t) * E_ + 2 * tid];
            #pragma unroll
            for (int dq = 0; dq < 8; ++dq) {
                float4 wv = *(const float4*)&eoT[t][dq * 4];
                acc[dq * 4 + 0].x += wv.x * ev.x; acc[dq * 4 + 0].y += wv.x * ev.y;
                acc[dq * 4 + 1].x += wv.y * ev.x; acc[dq * 4 + 1].y += wv.y * ev.y;
                acc[dq * 4 + 2].x += wv.z * ev.x; acc[dq * 4 + 2].y += wv.z * ev.y;
                acc[dq * 4 + 3].x += wv.w * ev.x; acc[dq * 4 + 3].y += wv.w * ev.y;
            }
        }
    }
    #pragma unroll
    for (int d = 0; d < 32; ++d)
        *(float2*)&cout[((size_t)b * TD + d0 + d) * E_ + 2 * tid] = acc[d];
}

// ---------------------------------------------------------------------------
extern "C" void kernel_launch(void* const* d_in, const int* in_sizes, int n_in,
                              void* d_out, int out_size, void* d_ws, size_t ws_size,
                              hipStream_t stream) {
    const float* enc  = (const float*)d_in[0];
    const float* dec  = (const float*)d_in[1];
    const float* cw   = (const float*)d_in[2];
    const float* cb   = (const float*)d_in[3];
    const float* wloc = (const float*)d_in[4];
    const float* va   = (const float*)d_in[5];
    const float* ba   = (const float*)d_in[6];

    float* c_out = (float*)d_out;                          // B*TD*E
    float* e_out = (float*)d_out + (size_t)B_ * TD * E_;   // B*TD*TE

    float* ws  = (float*)d_ws;
    float* prG = ws;                                       // 2*B*TE
    float* paG = ws + 2 * (size_t)B_ * TE;                 // 2*B*TE
    float* PsG = ws + 4 * (size_t)B_ * TE;                 // 2*B*NCH
    unsigned short* WTh = (unsigned short*)(PsG + 2 * (size_t)B_ * NCH);
    unsigned short* WTl = WTh + 512 * F_;
    int* flags = (int*)(WTl + 512 * F_);                   // B*NCH ints

    prep_kernel<<<1, 512, 0, stream>>>(wloc, WTh, WTl, flags);

    persist_kernel<<<NBLK, 512, 0, stream>>>(
        enc, dec, cw, cb, WTh, WTl, va, ba,
        prG, paG, PsG, e_out, flags);

    context_kernel<<<dim3(TD / 32, B_), 256, 0, stream>>>(e_out, enc, c_out);
}

// Round 3
// 8326.566 us; speedup vs baseline: 1.1356x; 1.1053x over previous
//
#include <hip/hip_runtime.h>
#include <hip/hip_fp16.h>
#include <math.h>

#define B_    32
#define TE    1024
#define TD    512
#define E_    512
#define F_    32
#define K_    31
#define KH    15
#define CHUNK 64
#define NCH   (TE / CHUNK)        // 16 chunks per batch row
#define NBLK  (B_ * NCH)          // 512 blocks = 2/CU x 256 CU, all resident

typedef __attribute__((ext_vector_type(8))) short short8;
typedef __attribute__((ext_vector_type(4))) float f32x4;

__device__ __forceinline__ unsigned short f2bf(float x) {   // RNE f32->bf16
    unsigned u = __float_as_uint(x);
    unsigned r = (u + 0x7fffu + ((u >> 16) & 1u)) >> 16;
    return (unsigned short)r;
}
__device__ __forceinline__ float bf2f(unsigned short h) {
    return __uint_as_float(((unsigned)h) << 16);
}

// Agent-scope accessors: cross-XCD coherent without cache-wide invalidates.
__device__ __forceinline__ float gldf(const float* p) {
    return __hip_atomic_load(p, __ATOMIC_RELAXED, __HIP_MEMORY_SCOPE_AGENT);
}
__device__ __forceinline__ void gstf(float* p, float v) {
    __hip_atomic_store(p, v, __ATOMIC_RELAXED, __HIP_MEMORY_SCOPE_AGENT);
}

// ---------------------------------------------------------------------------
// Prologue (once per call): w_loc (F,U row-major) -> transposed bf16 hi/lo
// [u][c] for direct B-fragment loads.  Also zero-inits the step flags.
// ---------------------------------------------------------------------------
__global__ void prep_kernel(const float* __restrict__ wloc,
                            unsigned short* __restrict__ WTh,
                            unsigned short* __restrict__ WTl,
                            int* __restrict__ flags)
{
    const int u = threadIdx.x;                 // 512 threads
    #pragma unroll
    for (int c = 0; c < F_; ++c) {
        float x = wloc[c * 512 + u];
        unsigned short h = f2bf(x);
        float lo = x - bf2f(h);
        WTh[u * F_ + c] = h;
        WTl[u * F_ + c] = f2bf(lo);
    }
    __hip_atomic_store(&flags[u], 0, __ATOMIC_RELAXED, __HIP_MEMORY_SCOPE_AGENT);
}

// ---------------------------------------------------------------------------
// Persistent kernel (plain launch; co-residency by resource arithmetic:
// <=128 VGPR -> 2 blocks/CU by waves; LDS 75.1KB*2 = 150KB <= 160KB).
// enc tile (step-invariant) staged ONCE in LDS as f16, transposed [u][t]
// with XOR swizzle t' = t ^ ((u&15)<<2): epilogue reads one conflict-free
// ds_read_b64 per (tt,ut) instead of 64 scattered global loads per lane.
// q+b_a folded into the MFMA C initializer.
// Inter-step sync = per-batch flag barrier (16 blocks), agent-scope atomics,
// parity double-buffer (see round-2 clobber analysis).
// ---------------------------------------------------------------------------
__global__ __launch_bounds__(512, 4)
void persist_kernel(const float* __restrict__ enc,   // B,TE,E
                    const float* __restrict__ dec,   // B,TD,E
                    const float* __restrict__ cw,    // K,1,F
                    const float* __restrict__ cb,    // F
                    const unsigned short* __restrict__ WTh, // U,F bf16 hi
                    const unsigned short* __restrict__ WTl, // U,F bf16 lo
                    const float* __restrict__ va,    // U
                    const float* __restrict__ ba,    // U
                    float* __restrict__ prG,         // 2,B,TE   exp(e)
                    float* __restrict__ paG,         // 2,B,TE   cum align
                    float* __restrict__ PsG,         // 2,B,NCH  partial sums
                    float* __restrict__ eout,        // B,TD,TE
                    int*   __restrict__ flags)       // B,NCH  steps completed
{
    __shared__ __align__(16) __half encS[E_ * CHUNK];         // 64 KB, [u][t^]
    __shared__ __align__(16) unsigned short fThS[CHUNK * F_]; // A-frag hi [t][c]
    __shared__ __align__(16) unsigned short fTlS[CHUNK * F_]; // A-frag lo
    __shared__ float paW[CHUNK + 2 * KH + 4];                 // 98
    __shared__ float redT[CHUNK][9];                          // [t][wave], pad
    __shared__ float prS[CHUNK];                              // own exp(e), s-1
    __shared__ float paS[CHUNK];                              // own cum align

    const int tid   = threadIdx.x;
    const int g     = tid & 63;
    const int w     = tid >> 6;               // wave 0..7
    const int q     = g >> 4;                 // quad 0..3
    const int n16   = g & 15;
    const int b     = blockIdx.x >> 4;
    const int chunk = blockIdx.x & 15;
    const int t0    = chunk * CHUNK;
    const float L2E = 1.4426950408889634f;
    const float KK  = 2.885390081777927f;     // 2*log2(e)

    // ---- hoisted: B-fragments, va/ba, conv weights in regs (per session) --
    short8 bh[4], bl[4];
    int uu[4]; float vv[4], baR[4];
    #pragma unroll
    for (int ut = 0; ut < 4; ++ut) {
        uu[ut]  = w * 64 + ut * 16 + n16;
        bh[ut]  = ((const short8*)WTh)[uu[ut] * 4 + q];
        bl[ut]  = ((const short8*)WTl)[uu[ut] * 4 + q];
        vv[ut]  = va[uu[ut]];
        baR[ut] = ba[uu[ut]];
    }
    float cwR[K_];                            // conv weights for c = tid&31
    #pragma unroll
    for (int k = 0; k < K_; ++k) cwR[k] = cw[k * F_ + (tid & 31)];
    const float cbR = cb[tid & 31];

    // ---- stage enc tile -> LDS f16, transposed [u][t ^ ((u&15)<<2)] ----
    for (int i = tid; i < CHUNK * E_ / 4; i += 512) {
        const int t  = (i * 4) >> 9;          // 0..63
        const int u0 = (i * 4) & 511;
        float4 v = *(const float4*)&enc[((size_t)b * TE + t0 + t) * E_ + u0];
        #pragma unroll
        for (int j = 0; j < 4; ++j) {
            const int u  = u0 + j;
            const int tp = t ^ ((u & 15) << 2);
            encS[u * CHUNK + tp] = __float2half(((const float*)&v)[j]);
        }
    }
    // (first read of encS is after >=2 __syncthreads below)

    int* myf = flags + b * NCH;
    const size_t rowB = (size_t)b * TE + t0;

    for (int s = 0; s < TD; ++s) {
        const int rp = (s + 1) & 1;           // parity of step s-1 buffers
        const int wp = s & 1;                 // parity of step s buffers

        // prefetch query row (no dependency on sync -> hides latency)
        const float* qrow = dec + ((size_t)b * TD + s) * E_;
        float qb[4];
        #pragma unroll
        for (int ut = 0; ut < 4; ++ut) qb[ut] = qrow[uu[ut]] + baR[ut];

        if (s == 0) {
            if (tid < CHUNK + 2 * KH + 4) paW[tid] = 0.0f;
            if (tid < CHUNK) {
                paS[tid] = 0.0f;
                gstf(&paG[wp * (B_ * TE) + rowB + tid], 0.0f);
            }
        } else {
            // ---- per-batch barrier: all 16 chunks finished step s-1 ----
            if (tid < NCH) {
                while (__hip_atomic_load(&myf[tid], __ATOMIC_RELAXED,
                                         __HIP_MEMORY_SCOPE_AGENT) < s)
                    __builtin_amdgcn_s_sleep(1);
            }
            __syncthreads();

            // per-wave redundant Ps sum (no extra barrier)
            float S = 0.0f;
            if (g < 16) S = gldf(&PsG[rp * (B_ * NCH) + b * NCH + g]);
            S += __shfl_xor(S, 1); S += __shfl_xor(S, 2);
            S += __shfl_xor(S, 4); S += __shfl_xor(S, 8);
            S = __shfl(S, 0);
            const float inv = 1.0f / S;

            if (tid < CHUNK) {
                // own chunk: finish softmax s-1, update cum align, publish
                float pn  = prS[tid] * inv;
                float pan = paS[tid] + pn;
                paS[tid]      = pan;
                paW[KH + tid] = pan;
                eout[((size_t)b * TD + (s - 1)) * TE + t0 + tid] = pn;
                gstf(&paG[wp * (B_ * TE) + rowB + tid], pan);
            } else if (tid < CHUNK + 2 * KH) {
                // halo from neighbors (published step s-1 data)
                int hh = tid - CHUNK;                       // 0..29
                int t  = (hh < KH) ? (t0 - KH + hh) : (t0 + CHUNK + (hh - KH));
                int wi = (hh < KH) ? hh : (CHUNK + hh);
                float v = 0.0f;
                if (t >= 0 && t < TE) {
                    size_t off = (size_t)rp * (B_ * TE) + (size_t)b * TE + t;
                    v = gldf(&paG[off]) + gldf(&prG[off]) * inv;
                }
                paW[wi] = v;
            } else if (tid < CHUNK + 2 * KH + 4) {
                paW[tid] = 0.0f;                            // pad 94..97
            }
        }
        __syncthreads();

        // ---- conv -> fT bf16 hi/lo in A-operand layout [t][c] ----
        {
            const int ts   = tid >> 5;            // 0..15, 4 t each
            const int base = ts * 4;
            const int c    = tid & 31;
            float pw[34];
            #pragma unroll
            for (int m = 0; m < 34; ++m) pw[m] = paW[base + m];
            float a0 = cbR, a1 = cbR, a2 = cbR, a3 = cbR;
            #pragma unroll
            for (int k = 0; k < K_; ++k) {
                float wv = cwR[k];
                a0 = fmaf(wv, pw[k],     a0);
                a1 = fmaf(wv, pw[k + 1], a1);
                a2 = fmaf(wv, pw[k + 2], a2);
                a3 = fmaf(wv, pw[k + 3], a3);
            }
            float av[4] = {a0, a1, a2, a3};
            #pragma unroll
            for (int i = 0; i < 4; ++i) {
                unsigned short h = f2bf(av[i]);
                fThS[(base + i) * F_ + c] = h;
                fTlS[(base + i) * F_ + c] = f2bf(av[i] - bf2f(h));
            }
        }
        __syncthreads();

        // ---- MFMA matmul + fused epilogue, one t-tile at a time ----
        const short8* AH = (const short8*)fThS;
        const short8* AL = (const short8*)fTlS;
        #pragma unroll
        for (int tt = 0; tt < 4; ++tt) {
            const int tp = (tt * 16 + q * 4) ^ (n16 << 2);   // swizzled t idx
            short8 ah = AH[(tt * 16 + n16) * 4 + q];
            short8 al = AL[(tt * 16 + n16) * 4 + q];
            f32x4 acc[4];
            float ef[4][4];
            #pragma unroll
            for (int ut = 0; ut < 4; ++ut) {
                uint2 ev = *(const uint2*)&encS[uu[ut] * CHUNK + tp];
                float2 e01 = __half22float2(*(const __half2*)&ev.x);
                float2 e23 = __half22float2(*(const __half2*)&ev.y);
                ef[ut][0] = e01.x; ef[ut][1] = e01.y;
                ef[ut][2] = e23.x; ef[ut][3] = e23.y;
                acc[ut] = (f32x4){qb[ut], qb[ut], qb[ut], qb[ut]};
                acc[ut] = __builtin_amdgcn_mfma_f32_16x16x32_bf16(ah, bh[ut], acc[ut], 0, 0, 0);
                acc[ut] = __builtin_amdgcn_mfma_f32_16x16x32_bf16(al, bh[ut], acc[ut], 0, 0, 0);
                acc[ut] = __builtin_amdgcn_mfma_f32_16x16x32_bf16(ah, bl[ut], acc[ut], 0, 0, 0);
            }
            #pragma unroll
            for (int r = 0; r < 4; ++r) {
                const int tl = tt * 16 + q * 4 + r;
                float sa = 0.0f;
                #pragma unroll
                for (int ut = 0; ut < 4; ++ut) {
                    float x  = acc[ut][r] + ef[ut][r];
                    float rr = __builtin_amdgcn_exp2f(x * KK);       // e^{2x}
                    float th = fmaf(-2.0f, __builtin_amdgcn_rcpf(rr + 1.0f), 1.0f);
                    sa = fmaf(vv[ut], th, sa);
                }
                sa += __shfl_xor(sa, 1);
                sa += __shfl_xor(sa, 2);
                sa += __shfl_xor(sa, 4);
                sa += __shfl_xor(sa, 8);
                if (n16 == 0) redT[tl][w] = sa;
            }
        }
        __syncthreads();

        // ---- final: sum 8 wave-partials per t, exp, publish pr + Ps ----
        if (tid < CHUNK) {
            float e = 0.0f;
            #pragma unroll
            for (int k = 0; k < 8; ++k) e += redT[tid][k];
            // max-free softmax: |e| <= sum|v_a| <= 25.6 -> exp2 arg <= 37
            float p = __builtin_amdgcn_exp2f(e * L2E);
            prS[tid] = p;
            gstf(&prG[wp * (B_ * TE) + rowB + tid], p);
            float sp = p;
            #pragma unroll
            for (int off = 32; off; off >>= 1) sp += __shfl_xor(sp, off);
            if (tid == 0) {
                gstf(&PsG[wp * (B_ * NCH) + b * NCH + chunk], sp);
                asm volatile("s_waitcnt vmcnt(0)" ::: "memory");
                __hip_atomic_store(&myf[chunk], s + 1, __ATOMIC_RELAXED,
                                   __HIP_MEMORY_SCOPE_AGENT);
            }
        }
        // no trailing barrier needed: next iter's post-wait __syncthreads
        // orders waves 1..7 behind wave 0; LDS hazards covered per phase.
    }

    // ---- tail: normalize last step (parity (TD-1)&1 == 1) into eout ----
    if (tid < NCH) {
        while (__hip_atomic_load(&myf[tid], __ATOMIC_RELAXED,
                                 __HIP_MEMORY_SCOPE_AGENT) < TD)
            __builtin_amdgcn_s_sleep(1);
    }
    __syncthreads();
    if (tid < CHUNK) {
        float S = 0.0f;
        if (g < 16) S = gldf(&PsG[1 * (B_ * NCH) + b * NCH + g]);
        S += __shfl_xor(S, 1); S += __shfl_xor(S, 2);
        S += __shfl_xor(S, 4); S += __shfl_xor(S, 8);
        S = __shfl(S, 0);
        float pn = prS[tid] * (1.0f / S);
        eout[((size_t)b * TD + (TD - 1)) * TE + t0 + tid] = pn;
    }
}

// ---------------------------------------------------------------------------
// Context matmul: c[b,d,e] = sum_t eo[b,d,t] * enc[b,t,e]
// ---------------------------------------------------------------------------
__global__ __launch_bounds__(256)
void context_kernel(const float* __restrict__ eo,   // B,TD,TE
                    const float* __restrict__ enc,  // B,TE,E
                    float* __restrict__ cout)       // B,TD,E
{
    __shared__ float eoT[64][36];
    const int b = blockIdx.y, d0 = blockIdx.x * 32, tid = threadIdx.x;

    float2 acc[32];
    #pragma unroll
    for (int d = 0; d < 32; ++d) { acc[d].x = 0.0f; acc[d].y = 0.0f; }

    for (int tc = 0; tc < TE / 64; ++tc) {
        __syncthreads();
        #pragma unroll
        for (int r = 0; r < 8; ++r) {
            int lin = r * 256 + tid;
            int d = lin >> 6, t = lin & 63;
            eoT[t][d] = eo[((size_t)b * TD + d0 + d) * TE + tc * 64 + t];
        }
        __syncthreads();
        #pragma unroll 4
        for (int t = 0; t < 64; ++t) {
            float2 ev = *(const float2*)&enc[((size_t)b * TE + tc * 64 + t) * E_ + 2 * tid];
            #pragma unroll
            for (int dq = 0; dq < 8; ++dq) {
                float4 wv = *(const float4*)&eoT[t][dq * 4];
                acc[dq * 4 + 0].x += wv.x * ev.x; acc[dq * 4 + 0].y += wv.x * ev.y;
                acc[dq * 4 + 1].x += wv.y * ev.x; acc[dq * 4 + 1].y += wv.y * ev.y;
                acc[dq * 4 + 2].x += wv.z * ev.x; acc[dq * 4 + 2].y += wv.z * ev.y;
                acc[dq * 4 + 3].x += wv.w * ev.x; acc[dq * 4 + 3].y += wv.w * ev.y;
            }
        }
    }
    #pragma unroll
    for (int d = 0; d < 32; ++d)
        *(float2*)&cout[((size_t)b * TD + d0 + d) * E_ + 2 * tid] = acc[d];
}

// ---------------------------------------------------------------------------
extern "C" void kernel_launch(void* const* d_in, const int* in_sizes, int n_in,
                              void* d_out, int out_size, void* d_ws, size_t ws_size,
                              hipStream_t stream) {
    const float* enc  = (const float*)d_in[0];
    const float* dec  = (const float*)d_in[1];
    const float* cw   = (const float*)d_in[2];
    const float* cb   = (const float*)d_in[3];
    const float* wloc = (const float*)d_in[4];
    const float* va   = (const float*)d_in[5];
    const float* ba   = (const float*)d_in[6];

    float* c_out = (float*)d_out;                          // B*TD*E
    float* e_out = (float*)d_out + (size_t)B_ * TD * E_;   // B*TD*TE

    float* ws  = (float*)d_ws;
    float* prG = ws;                                       // 2*B*TE
    float* paG = ws + 2 * (size_t)B_ * TE;                 // 2*B*TE
    float* PsG = ws + 4 * (size_t)B_ * TE;                 // 2*B*NCH
    unsigned short* WTh = (unsigned short*)(PsG + 2 * (size_t)B_ * NCH);
    unsigned short* WTl = WTh + 512 * F_;
    int* flags = (int*)(WTl + 512 * F_);                   // B*NCH ints

    prep_kernel<<<1, 512, 0, stream>>>(wloc, WTh, WTl, flags);

    persist_kernel<<<NBLK, 512, 0, stream>>>(
        enc, dec, cw, cb, WTh, WTl, va, ba,
        prG, paG, PsG, e_out, flags);

    context_kernel<<<dim3(TD / 32, B_), 256, 0, stream>>>(e_out, enc, c_out);
}